// Round 1
// baseline (1885.603 us; speedup 1.0000x reference)
//
#include <hip/hip_runtime.h>
#include <math.h>

constexpr int B  = 32;
constexpr int T0 = 2048;
constexpr int D  = 512;
constexpr int NCHUNK = 8;
constexpr int CHUNK  = T0 / NCHUNK;

// ws layout (in floats)
constexpr size_t SZ_PART  = (size_t)B * D * NCHUNK * 7;     // stats partials
constexpr size_t OFF_PART = 0;
constexpr size_t OFF_TDA  = OFF_PART + SZ_PART;             // B*7
constexpr size_t OFF_ATTN = OFF_TDA + (size_t)B * 7;        // B*D
constexpr size_t OFF_INJ  = OFF_ATTN + (size_t)B * D;       // 3*B*D
constexpr size_t OFF_ALT  = OFF_INJ + 3ull * B * D;         // 3*B*D

// ---------------- stats: partial sums over t-chunks of level0 ----------------
__global__ __launch_bounds__(512) void k_stats_partial(const float* __restrict__ x,
                                                        float* __restrict__ part) {
  const int d = threadIdx.x;        // 0..511
  const int b = blockIdx.x;         // 0..31
  const int c = blockIdx.y;         // 0..7
  const int t0 = c * CHUNK;
  const float* base = x + (size_t)b * T0 * D + d;
  float S1 = 0.f, S2 = 0.f, St = 0.f, C = 0.f, A = 0.f;
  float mn = INFINITY, mx = -INFINITY;
  float xprev = (c > 0) ? base[(size_t)(t0 - 1) * D] : 0.0f;
  for (int t = t0; t < t0 + CHUNK; ++t) {
    float v = base[(size_t)t * D];
    S1 += v;
    S2 = fmaf(v, v, S2);
    St = fmaf((float)t, v, St);
    A += (t & 1) ? -v : v;
    mn = fminf(mn, v);
    mx = fmaxf(mx, v);
    if (t > 0) C = fmaf(xprev, v, C);   // pair (t-1, t)
    xprev = v;
  }
  float* p = part + (((size_t)(b * D + d)) * NCHUNK + c) * 7;
  p[0] = S1; p[1] = S2; p[2] = St; p[3] = C; p[4] = A; p[5] = mn; p[6] = mx;
}

// ------------- stats: fold chunks, compute 6 features, mean over d -----------
__global__ __launch_bounds__(512) void k_stats_reduce(const float* __restrict__ x,
                                                       const float* __restrict__ part,
                                                       float* __restrict__ tda) {
  const int d = threadIdx.x;
  const int b = blockIdx.x;
  float S1 = 0.f, S2 = 0.f, St = 0.f, C = 0.f;
  float mn = INFINITY, mx = -INFINITY;
  const float* p = part + ((size_t)(b * D + d)) * NCHUNK * 7;
  for (int c = 0; c < NCHUNK; ++c) {
    S1 += p[c * 7 + 0];
    S2 += p[c * 7 + 1];
    St += p[c * 7 + 2];
    C  += p[c * 7 + 3];
    mn = fminf(mn, p[c * 7 + 5]);
    mx = fmaxf(mx, p[c * 7 + 6]);
  }
  const float x0 = x[(size_t)b * T0 * D + d];
  const float xl = x[((size_t)b * T0 + T0 - 1) * D + d];
  const float Tf = (float)T0;
  const float mean = S1 / Tf;
  const float sxx  = S2 - S1 * S1 / Tf;                 // sum (x-mean)^2
  const float stdv = sqrtf(fmaxf(sxx / (Tf - 1.f), 0.f));
  // trend
  const float tbar = (Tf - 1.f) * 0.5f;
  const float Sic  = Tf * (Tf * Tf - 1.f) / 12.f;       // sum (t - tbar)^2
  const float tn   = St - tbar * S1;
  float trend = tn / sqrtf(sxx * Sic);
  if (isnan(trend)) trend = 0.f;
  // autocorr (lag 1): a = x[0..T-2], b = x[1..T-1]
  const float na = Tf - 1.f;
  const float Sa = S1 - xl, Sb = S1 - x0;
  const float an  = C - Sa * Sb / na;
  const float sa2 = (S2 - xl * xl) - Sa * Sa / na;
  const float sb2 = (S2 - x0 * x0) - Sb * Sb / na;
  float ac = an / sqrtf(sa2 * sb2);
  if (isnan(ac)) ac = 0.f;

  __shared__ float red[512];
  const float feats[6] = {mean, stdv, mn, mx, trend, ac};
  for (int f = 0; f < 6; ++f) {
    red[d] = feats[f];
    __syncthreads();
    for (int s = 256; s > 0; s >>= 1) {
      if (d < s) red[d] += red[d + s];
      __syncthreads();
    }
    if (d == 0) tda[b * 7 + f] = red[0] / (float)D;
    __syncthreads();
  }
  if (d == 0) tda[b * 7 + 6] = 0.f;   // centroid accumulated by FFT kernel
}

// -------- spectral centroid: 2048-pt Stockham FFT in LDS, 2 d's per block ----
__global__ __launch_bounds__(256) void k_fft_centroid(const float* __restrict__ x,
                                                       float* __restrict__ tda) {
  __shared__ float2 bufA[2048];
  __shared__ float2 bufB[2048];
  const int tid = threadIdx.x;
  const int e = blockIdx.x;   // d-pair index (fast dim → consecutive blocks share cache lines)
  const int b = blockIdx.y;
  const float* base = x + (size_t)b * T0 * D + 2 * e;
  #pragma unroll
  for (int r = 0; r < 8; ++r) {
    int t = r * 256 + tid;
    float2 v = *(const float2*)&base[(size_t)t * D];   // 8B-aligned (2e even)
    bufA[t] = v;
  }
  __syncthreads();
  float2* src = bufA;
  float2* dst = bufB;
  int l = 1024;
  for (int s = 0; s < 11; ++s) {
    const int m = 1 << s;
    #pragma unroll
    for (int qq = 0; qq < 4; ++qq) {
      int q = qq * 256 + tid;
      int j = q >> s;                       // q / m
      float ang = -(float)M_PI * (float)j / (float)l;
      float sw, cw;
      sincosf(ang, &sw, &cw);
      float2 a = src[q];
      float2 c = src[q + 1024];
      float2 sum = make_float2(a.x + c.x, a.y + c.y);
      float2 dif = make_float2(a.x - c.x, a.y - c.y);
      float2 tw  = make_float2(dif.x * cw - dif.y * sw, dif.x * sw + dif.y * cw);
      int o = q + (j << s);                 // q + j*m
      dst[o] = sum;
      dst[o + m] = tw;
    }
    __syncthreads();
    float2* tmp = src; src = dst; dst = tmp;
    l >>= 1;
  }
  // unpack two real spectra, accumulate k-weighted power sums over k=0..1023
  float numA = 0.f, denA = 0.f, numB = 0.f, denB = 0.f;
  #pragma unroll
  for (int r = 0; r < 4; ++r) {
    int k = r * 256 + tid;
    float2 zk = src[k];
    float2 zm = src[(2048 - k) & 2047];
    float arx = 0.5f * (zk.x + zm.x), ary = 0.5f * (zk.y - zm.y);
    float brx = 0.5f * (zk.y + zm.y), bry = 0.5f * (zm.x - zk.x);
    float pa = arx * arx + ary * ary;
    float pb = brx * brx + bry * bry;
    float kf = (float)k;
    numA = fmaf(kf, pa, numA); denA += pa;
    numB = fmaf(kf, pb, numB); denB += pb;
  }
  float* scratch = (float*)dst;   // free buffer
  float vals[4] = {numA, denA, numB, denB};
  float tot[4];
  for (int v = 0; v < 4; ++v) {
    __syncthreads();
    scratch[tid] = vals[v];
    __syncthreads();
    for (int s2 = 128; s2 > 0; s2 >>= 1) {
      if (tid < s2) scratch[tid] += scratch[tid + s2];
      __syncthreads();
    }
    tot[v] = scratch[0];
  }
  if (tid == 0) {
    float cA = tot[1] > 0.f ? tot[0] / tot[1] : 0.f;
    float cB = tot[3] > 0.f ? tot[2] / tot[3] : 0.f;
    if (isnan(cA)) cA = 0.f;
    if (isnan(cB)) cB = 0.f;
    atomicAdd(&tda[b * 7 + 6], (cA + cB) * (1.0f / (float)D));
  }
}

// --------------- attn = sigmoid(relu(tda@w1+b1)@w2+b2); inj_l -----------------
__global__ __launch_bounds__(512) void k_weights(const float* __restrict__ tda,
    const float* __restrict__ w1, const float* __restrict__ b1,
    const float* __restrict__ w2, const float* __restrict__ b2,
    const float* __restrict__ wi0, const float* __restrict__ bi0,
    const float* __restrict__ wi1, const float* __restrict__ bi1,
    const float* __restrict__ wi2, const float* __restrict__ bi2,
    float* __restrict__ attn, float* __restrict__ inj) {
  const int b = blockIdx.x;
  const int j = threadIdx.x;
  __shared__ float td[7];
  __shared__ float h[512];
  if (j < 7) td[j] = tda[b * 7 + j];
  __syncthreads();
  float a = b1[j];
  #pragma unroll
  for (int f = 0; f < 7; ++f) a = fmaf(td[f], w1[f * D + j], a);
  h[j] = fmaxf(a, 0.0f);
  __syncthreads();
  float a2 = b2[j];
  for (int k = 0; k < D; ++k) a2 = fmaf(h[k], w2[k * D + j], a2);
  attn[(size_t)b * D + j] = 1.0f / (1.0f + expf(-a2));
  const float* wis[3] = {wi0, wi1, wi2};
  const float* bis[3] = {bi0, bi1, bi2};
  #pragma unroll
  for (int l = 0; l < 3; ++l) {
    float ai = bis[l][j];
    #pragma unroll
    for (int f = 0; f < 7; ++f) ai = fmaf(td[f], wis[l][f * D + j], ai);
    inj[(size_t)l * B * D + (size_t)b * D + j] = 0.3f * ai;
  }
}

// ------------------- alternating sums A[b,d] = sum (-1)^t x ------------------
__global__ __launch_bounds__(512) void k_altsum(const float* __restrict__ x,
                                                 float* __restrict__ A, int Tlen) {
  const int d = threadIdx.x;
  const int b = blockIdx.x;
  const int c = blockIdx.y;
  const int chunk = Tlen / 8;
  const int t0 = c * chunk;
  const float* base = x + (size_t)b * Tlen * D + d;
  float a = 0.f;
  for (int t = t0; t < t0 + chunk; ++t) {
    float v = base[(size_t)t * D];
    a += (t & 1) ? -v : v;
  }
  atomicAdd(&A[(size_t)b * D + d], a);
}

// ------ interp (closed-form 2x spectral upsample) + combine into output ------
// out[b, 2j,   d] = (high[2j]   - (low[j]/4 + (-1)^j A/(4S))) * attn + inj
// out[b, 2j+1, d] = (high[2j+1] - (1/4S) sum_t low[t] w[(j-t) mod S]) * attn + inj
// w[r] = (-1)^r * cot(pi (r+0.5) / S)
__global__ __launch_bounds__(256) void k_interp(const float* __restrict__ low,
                                                 const float* __restrict__ high,
                                                 const float* __restrict__ attn,
                                                 const float* __restrict__ inj,
                                                 const float* __restrict__ Aalt,
                                                 float* __restrict__ out, int S) {
  __shared__ float w_s[1024];
  __shared__ float x_s[64][128];
  const int tid  = threadIdx.x;
  const int b    = blockIdx.z;
  const int d0   = blockIdx.y * 128;
  const int j0   = blockIdx.x * 16;
  const int dthr = tid & 63;
  const int jthr = tid >> 6;

  for (int r = tid; r < S; r += 256) {
    double arg = M_PI * ((double)r + 0.5) / (double)S;
    double cotv = cos(arg) / sin(arg);
    w_s[r] = (r & 1) ? -(float)cotv : (float)cotv;
  }

  const float* lowb  = low  + (size_t)b * S * D;
  const float* highb = high + (size_t)b * (2 * S) * D;
  float*       outb  = out  + (size_t)b * (2 * S) * D;

  float acc[4][2] = {};
  for (int t0 = 0; t0 < S; t0 += 64) {
    __syncthreads();   // covers w_s fill before first use + x_s reuse
    #pragma unroll
    for (int r = 0; r < 32; ++r) {
      int idx = r * 256 + tid;
      int tt = idx >> 7, dd = idx & 127;
      x_s[tt][dd] = lowb[(size_t)(t0 + tt) * D + d0 + dd];
    }
    __syncthreads();
    #pragma unroll 4
    for (int tt = 0; tt < 64; ++tt) {
      float xv0 = x_s[tt][dthr];
      float xv1 = x_s[tt][64 + dthr];
      int ridx = j0 + jthr - t0 - tt;
      #pragma unroll
      for (int jj = 0; jj < 4; ++jj) {
        float wv = w_s[(ridx + 4 * jj) & (S - 1)];
        acc[jj][0] = fmaf(xv0, wv, acc[jj][0]);
        acc[jj][1] = fmaf(xv1, wv, acc[jj][1]);
      }
    }
  }

  const float inv4S = 1.0f / (4.0f * (float)S);
  #pragma unroll
  for (int dd = 0; dd < 2; ++dd) {
    const int d = d0 + dd * 64 + dthr;
    const float at = attn[(size_t)b * D + d];
    const float in = inj [(size_t)b * D + d];
    const float Av = Aalt[(size_t)b * D + d] * inv4S;
    #pragma unroll
    for (int jj = 0; jj < 4; ++jj) {
      const int j = j0 + jthr + 4 * jj;
      int m = 2 * j + 1;                                   // odd row
      float res = acc[jj][dd] * inv4S;
      outb[(size_t)m * D + d] = (highb[(size_t)m * D + d] - res) * at + in;
      m = 2 * j;                                           // even row
      float lv = lowb[(size_t)j * D + d];
      float rese = fmaf(0.25f, lv, (j & 1) ? -Av : Av);
      outb[(size_t)m * D + d] = (highb[(size_t)m * D + d] - rese) * at + in;
    }
  }
}

// ------------------------------ copy level3 ----------------------------------
__global__ void k_copy4(const float4* __restrict__ in, float4* __restrict__ out, int n) {
  int i = blockIdx.x * blockDim.x + threadIdx.x;
  if (i < n) out[i] = in[i];
}

extern "C" void kernel_launch(void* const* d_in, const int* in_sizes, int n_in,
                              void* d_out, int out_size, void* d_ws, size_t ws_size,
                              hipStream_t stream) {
  const float* level0 = (const float*)d_in[0];
  const float* level1 = (const float*)d_in[1];
  const float* level2 = (const float*)d_in[2];
  const float* level3 = (const float*)d_in[3];
  const float* w1  = (const float*)d_in[4];
  const float* b1  = (const float*)d_in[5];
  const float* w2  = (const float*)d_in[6];
  const float* b2  = (const float*)d_in[7];
  const float* wi0 = (const float*)d_in[8];
  const float* bi0 = (const float*)d_in[9];
  const float* wi1 = (const float*)d_in[10];
  const float* bi1 = (const float*)d_in[11];
  const float* wi2 = (const float*)d_in[12];
  const float* bi2 = (const float*)d_in[13];

  float* ws   = (float*)d_ws;
  float* part = ws + OFF_PART;
  float* tda  = ws + OFF_TDA;
  float* attn = ws + OFF_ATTN;
  float* inj  = ws + OFF_INJ;
  float* alt  = ws + OFF_ALT;

  float* out0 = (float*)d_out;                       // (32,2048,512)
  float* out1 = out0 + (size_t)B * 2048 * D;         // (32,1024,512)
  float* out2 = out1 + (size_t)B * 1024 * D;         // (32, 512,512)
  float* out3 = out2 + (size_t)B * 512 * D;          // (32, 256,512)

  hipMemsetAsync(alt, 0, 3ull * B * D * sizeof(float), stream);

  k_stats_partial<<<dim3(B, NCHUNK), 512, 0, stream>>>(level0, part);
  k_stats_reduce<<<B, 512, 0, stream>>>(level0, part, tda);
  k_fft_centroid<<<dim3(256, B), 256, 0, stream>>>(level0, tda);
  k_weights<<<B, 512, 0, stream>>>(tda, w1, b1, w2, b2, wi0, bi0, wi1, bi1, wi2, bi2,
                                   attn, inj);

  k_altsum<<<dim3(B, 8), 512, 0, stream>>>(level1, alt + 0 * B * D, 1024);
  k_altsum<<<dim3(B, 8), 512, 0, stream>>>(level2, alt + 1 * B * D, 512);
  k_altsum<<<dim3(B, 8), 512, 0, stream>>>(level3, alt + 2 * B * D, 256);

  k_interp<<<dim3(1024 / 16, 4, B), 256, 0, stream>>>(level1, level0, attn,
           inj + 0ull * B * D, alt + 0 * B * D, out0, 1024);
  k_interp<<<dim3(512 / 16, 4, B), 256, 0, stream>>>(level2, level1, attn,
           inj + 1ull * B * D, alt + 1 * B * D, out1, 512);
  k_interp<<<dim3(256 / 16, 4, B), 256, 0, stream>>>(level3, level2, attn,
           inj + 2ull * B * D, alt + 2 * B * D, out2, 256);

  k_copy4<<<(B * 256 * D / 4 + 255) / 256, 256, 0, stream>>>(
      (const float4*)level3, (float4*)out3, B * 256 * D / 4);
}

// Round 2
// 641.996 us; speedup vs baseline: 2.9371x; 2.9371x over previous
//
#include <hip/hip_runtime.h>
#include <math.h>

constexpr int B  = 32;
constexpr int T0 = 2048;
constexpr int D  = 512;
constexpr int NCHUNK = 8;
constexpr int CHUNK  = T0 / NCHUNK;

// ws layout (in floats)
constexpr size_t SZ_PART  = (size_t)B * D * NCHUNK * 7;     // stats partials
constexpr size_t OFF_PART = 0;
constexpr size_t OFF_TDA  = OFF_PART + SZ_PART;             // B*7
constexpr size_t OFF_ATTN = OFF_TDA + (size_t)B * 7;        // B*D
constexpr size_t OFF_INJ  = OFF_ATTN + (size_t)B * D;       // 3*B*D

// ---------------- stats: partial sums over t-chunks of level0 ----------------
__global__ __launch_bounds__(512) void k_stats_partial(const float* __restrict__ x,
                                                        float* __restrict__ part) {
  const int d = threadIdx.x;        // 0..511
  const int b = blockIdx.x;         // 0..31
  const int c = blockIdx.y;         // 0..7
  const int t0 = c * CHUNK;
  const float* base = x + (size_t)b * T0 * D + d;
  float S1 = 0.f, S2 = 0.f, St = 0.f, C = 0.f;
  float mn = INFINITY, mx = -INFINITY;
  float xprev = (c > 0) ? base[(size_t)(t0 - 1) * D] : 0.0f;
  for (int t = t0; t < t0 + CHUNK; ++t) {
    float v = base[(size_t)t * D];
    S1 += v;
    S2 = fmaf(v, v, S2);
    St = fmaf((float)t, v, St);
    mn = fminf(mn, v);
    mx = fmaxf(mx, v);
    if (t > 0) C = fmaf(xprev, v, C);   // pair (t-1, t)
    xprev = v;
  }
  float* p = part + (((size_t)(b * D + d)) * NCHUNK + c) * 7;
  p[0] = S1; p[1] = S2; p[2] = St; p[3] = C; p[4] = 0.f; p[5] = mn; p[6] = mx;
}

// ------------- stats: fold chunks, compute 6 features, mean over d -----------
__global__ __launch_bounds__(512) void k_stats_reduce(const float* __restrict__ x,
                                                       const float* __restrict__ part,
                                                       float* __restrict__ tda) {
  const int d = threadIdx.x;
  const int b = blockIdx.x;
  float S1 = 0.f, S2 = 0.f, St = 0.f, C = 0.f;
  float mn = INFINITY, mx = -INFINITY;
  const float* p = part + ((size_t)(b * D + d)) * NCHUNK * 7;
  for (int c = 0; c < NCHUNK; ++c) {
    S1 += p[c * 7 + 0];
    S2 += p[c * 7 + 1];
    St += p[c * 7 + 2];
    C  += p[c * 7 + 3];
    mn = fminf(mn, p[c * 7 + 5]);
    mx = fmaxf(mx, p[c * 7 + 6]);
  }
  const float x0 = x[(size_t)b * T0 * D + d];
  const float xl = x[((size_t)b * T0 + T0 - 1) * D + d];
  const float Tf = (float)T0;
  const float mean = S1 / Tf;
  const float sxx  = S2 - S1 * S1 / Tf;                 // sum (x-mean)^2
  const float stdv = sqrtf(fmaxf(sxx / (Tf - 1.f), 0.f));
  // trend
  const float tbar = (Tf - 1.f) * 0.5f;
  const float Sic  = Tf * (Tf * Tf - 1.f) / 12.f;       // sum (t - tbar)^2
  const float tn   = St - tbar * S1;
  float trend = tn / sqrtf(sxx * Sic);
  if (isnan(trend)) trend = 0.f;
  // autocorr (lag 1): a = x[0..T-2], b = x[1..T-1]
  const float na = Tf - 1.f;
  const float Sa = S1 - xl, Sb = S1 - x0;
  const float an  = C - Sa * Sb / na;
  const float sa2 = (S2 - xl * xl) - Sa * Sa / na;
  const float sb2 = (S2 - x0 * x0) - Sb * Sb / na;
  float ac = an / sqrtf(sa2 * sb2);
  if (isnan(ac)) ac = 0.f;

  __shared__ float red[512];
  const float feats[6] = {mean, stdv, mn, mx, trend, ac};
  for (int f = 0; f < 6; ++f) {
    red[d] = feats[f];
    __syncthreads();
    for (int s = 256; s > 0; s >>= 1) {
      if (d < s) red[d] += red[d + s];
      __syncthreads();
    }
    if (d == 0) tda[b * 7 + f] = red[0] / (float)D;
    __syncthreads();
  }
  if (d == 0) tda[b * 7 + 6] = 0.f;   // centroid accumulated by FFT kernel
}

// -------- spectral centroid: 2048-pt Stockham FFT in LDS, 2 d's per block ----
__global__ __launch_bounds__(256) void k_fft_centroid(const float* __restrict__ x,
                                                       float* __restrict__ tda) {
  __shared__ float2 bufA[2048];
  __shared__ float2 bufB[2048];
  const int tid = threadIdx.x;
  const int e = blockIdx.x;
  const int b = blockIdx.y;
  const float* base = x + (size_t)b * T0 * D + 2 * e;
  #pragma unroll
  for (int r = 0; r < 8; ++r) {
    int t = r * 256 + tid;
    float2 v = *(const float2*)&base[(size_t)t * D];
    bufA[t] = v;
  }
  __syncthreads();
  float2* src = bufA;
  float2* dst = bufB;
  int l = 1024;
  for (int s = 0; s < 11; ++s) {
    const int m = 1 << s;
    #pragma unroll
    for (int qq = 0; qq < 4; ++qq) {
      int q = qq * 256 + tid;
      int j = q >> s;
      float ang = -(float)M_PI * (float)j / (float)l;
      float sw, cw;
      sincosf(ang, &sw, &cw);
      float2 a = src[q];
      float2 c = src[q + 1024];
      float2 sum = make_float2(a.x + c.x, a.y + c.y);
      float2 dif = make_float2(a.x - c.x, a.y - c.y);
      float2 tw  = make_float2(dif.x * cw - dif.y * sw, dif.x * sw + dif.y * cw);
      int o = q + (j << s);
      dst[o] = sum;
      dst[o + m] = tw;
    }
    __syncthreads();
    float2* tmp = src; src = dst; dst = tmp;
    l >>= 1;
  }
  float numA = 0.f, denA = 0.f, numB = 0.f, denB = 0.f;
  #pragma unroll
  for (int r = 0; r < 4; ++r) {
    int k = r * 256 + tid;
    float2 zk = src[k];
    float2 zm = src[(2048 - k) & 2047];
    float arx = 0.5f * (zk.x + zm.x), ary = 0.5f * (zk.y - zm.y);
    float brx = 0.5f * (zk.y + zm.y), bry = 0.5f * (zm.x - zk.x);
    float pa = arx * arx + ary * ary;
    float pb = brx * brx + bry * bry;
    float kf = (float)k;
    numA = fmaf(kf, pa, numA); denA += pa;
    numB = fmaf(kf, pb, numB); denB += pb;
  }
  float* scratch = (float*)dst;
  float vals[4] = {numA, denA, numB, denB};
  float tot[4];
  for (int v = 0; v < 4; ++v) {
    __syncthreads();
    scratch[tid] = vals[v];
    __syncthreads();
    for (int s2 = 128; s2 > 0; s2 >>= 1) {
      if (tid < s2) scratch[tid] += scratch[tid + s2];
      __syncthreads();
    }
    tot[v] = scratch[0];
  }
  if (tid == 0) {
    float cA = tot[1] > 0.f ? tot[0] / tot[1] : 0.f;
    float cB = tot[3] > 0.f ? tot[2] / tot[3] : 0.f;
    if (isnan(cA)) cA = 0.f;
    if (isnan(cB)) cB = 0.f;
    atomicAdd(&tda[b * 7 + 6], (cA + cB) * (1.0f / (float)D));
  }
}

// --------------- attn = sigmoid(relu(tda@w1+b1)@w2+b2); inj_l -----------------
__global__ __launch_bounds__(512) void k_weights(const float* __restrict__ tda,
    const float* __restrict__ w1, const float* __restrict__ b1,
    const float* __restrict__ w2, const float* __restrict__ b2,
    const float* __restrict__ wi0, const float* __restrict__ bi0,
    const float* __restrict__ wi1, const float* __restrict__ bi1,
    const float* __restrict__ wi2, const float* __restrict__ bi2,
    float* __restrict__ attn, float* __restrict__ inj) {
  const int b = blockIdx.x;
  const int j = threadIdx.x;
  __shared__ float td[7];
  __shared__ float h[512];
  if (j < 7) td[j] = tda[b * 7 + j];
  __syncthreads();
  float a = b1[j];
  #pragma unroll
  for (int f = 0; f < 7; ++f) a = fmaf(td[f], w1[f * D + j], a);
  h[j] = fmaxf(a, 0.0f);
  __syncthreads();
  float a2 = b2[j];
  for (int k = 0; k < D; ++k) a2 = fmaf(h[k], w2[k * D + j], a2);
  attn[(size_t)b * D + j] = 1.0f / (1.0f + expf(-a2));
  const float* wis[3] = {wi0, wi1, wi2};
  const float* bis[3] = {bi0, bi1, bi2};
  #pragma unroll
  for (int l = 0; l < 3; ++l) {
    float ai = bis[l][j];
    #pragma unroll
    for (int f = 0; f < 7; ++f) ai = fmaf(td[f], wis[l][f * D + j], ai);
    inj[(size_t)l * B * D + (size_t)b * D + j] = 0.3f * ai;
  }
}

// --------- FFT-based 2x spectral interp + combine -----------------------------
// Packed trick: z = low[:,2e] + i*low[:,2e+1]. Z = FFT_S(z).
// Routing (real 0/1 matrix => packing exact):
//   Y[k] = Z[k]        for k = 0..S/2
//   Y[S+m] = Z[m]      for m = S/2..S-1   (Z[S/2] used twice)
//   Y[k] = 0           otherwise
// y = IFFT_2S(Y) (unnormalized), res = y * 1/(4S)  [irfft 1/(2S) * ref scale 1/2]
// out = (high - res)*attn + inj
template<int S>
__global__ __launch_bounds__(256) void k_fft_interp(const float* __restrict__ low,
                                                     const float* __restrict__ high,
                                                     const float* __restrict__ attn,
                                                     const float* __restrict__ inj,
                                                     float* __restrict__ out) {
  constexpr int N2 = 2 * S;
  extern __shared__ float2 sh[];            // 2 * N2 float2
  float2* src = sh;
  float2* dst = sh + N2;
  const int tid = threadIdx.x;

  // XCD-friendly swizzle: 8 blocks sharing a 64B line -> same (presumed) XCD
  int L = blockIdx.x + 256 * blockIdx.y;    // gridDim = (256, 32)
  int rr = L & 7, g = L >> 3;
  int e = rr * 32 + (g & 31);               // d-pair index, 0..255
  int b = g >> 5;                           // batch, 0..31

  const float* lowb  = low  + (size_t)b * S  * D + 2 * e;
  const float* highb = high + (size_t)b * N2 * D + 2 * e;
  float*       outb  = out  + (size_t)b * N2 * D + 2 * e;

  for (int t = tid; t < S; t += 256)
    src[t] = *(const float2*)&lowb[(size_t)t * D];
  __syncthreads();

  // ---- forward S-point Stockham FFT (natural in/out, sign -1) ----
  {
    int l = S / 2;
    for (int s = 0; (1 << s) < S; ++s) {
      const int m = 1 << s;
      for (int q = tid; q < S / 2; q += 256) {
        int j = q >> s;
        float ang = -(float)M_PI * (float)j / (float)l;
        float sw, cw;
        sincosf(ang, &sw, &cw);
        float2 a = src[q];
        float2 c = src[q + S / 2];
        float2 sum = make_float2(a.x + c.x, a.y + c.y);
        float2 dif = make_float2(a.x - c.x, a.y - c.y);
        float2 tw  = make_float2(dif.x * cw - dif.y * sw, dif.x * sw + dif.y * cw);
        int o = q + (j << s);
        dst[o] = sum;
        dst[o + m] = tw;
      }
      __syncthreads();
      float2* tmp = src; src = dst; dst = tmp;
      l >>= 1;
    }
  }
  // src = Z[0..S)

  // ---- spectral routing into dst[0..N2) ----
  for (int k = tid; k < N2; k += 256) {
    float2 v = make_float2(0.f, 0.f);
    if (k <= S / 2)            v = src[k];
    else if (k >= 3 * S / 2)   v = src[k - S];
    dst[k] = v;
  }
  __syncthreads();
  { float2* tmp = src; src = dst; dst = tmp; }   // src = Y

  // ---- inverse N2-point Stockham FFT (sign +1, unnormalized) ----
  {
    int l = N2 / 2;
    for (int s = 0; (1 << s) < N2; ++s) {
      const int m = 1 << s;
      for (int q = tid; q < N2 / 2; q += 256) {
        int j = q >> s;
        float ang = (float)M_PI * (float)j / (float)l;
        float sw, cw;
        sincosf(ang, &sw, &cw);
        float2 a = src[q];
        float2 c = src[q + N2 / 2];
        float2 sum = make_float2(a.x + c.x, a.y + c.y);
        float2 dif = make_float2(a.x - c.x, a.y - c.y);
        float2 tw  = make_float2(dif.x * cw - dif.y * sw, dif.x * sw + dif.y * cw);
        int o = q + (j << s);
        dst[o] = sum;
        dst[o + m] = tw;
      }
      __syncthreads();
      float2* tmp = src; src = dst; dst = tmp;
      l >>= 1;
    }
  }
  // src = y (unnormalized), Re -> d=2e, Im -> d=2e+1

  const float inv4S = 1.0f / (4.0f * (float)S);
  const float2 at = *(const float2*)&attn[(size_t)b * D + 2 * e];
  const float2 in = *(const float2*)&inj [(size_t)b * D + 2 * e];
  for (int t = tid; t < N2; t += 256) {
    float2 y = src[t];
    float2 h = *(const float2*)&highb[(size_t)t * D];
    float2 o;
    o.x = (h.x - y.x * inv4S) * at.x + in.x;
    o.y = (h.y - y.y * inv4S) * at.y + in.y;
    *(float2*)&outb[(size_t)t * D] = o;
  }
}

// ------------------------------ copy level3 ----------------------------------
__global__ void k_copy4(const float4* __restrict__ in, float4* __restrict__ out, int n) {
  int i = blockIdx.x * blockDim.x + threadIdx.x;
  if (i < n) out[i] = in[i];
}

extern "C" void kernel_launch(void* const* d_in, const int* in_sizes, int n_in,
                              void* d_out, int out_size, void* d_ws, size_t ws_size,
                              hipStream_t stream) {
  const float* level0 = (const float*)d_in[0];
  const float* level1 = (const float*)d_in[1];
  const float* level2 = (const float*)d_in[2];
  const float* level3 = (const float*)d_in[3];
  const float* w1  = (const float*)d_in[4];
  const float* b1  = (const float*)d_in[5];
  const float* w2  = (const float*)d_in[6];
  const float* b2  = (const float*)d_in[7];
  const float* wi0 = (const float*)d_in[8];
  const float* bi0 = (const float*)d_in[9];
  const float* wi1 = (const float*)d_in[10];
  const float* bi1 = (const float*)d_in[11];
  const float* wi2 = (const float*)d_in[12];
  const float* bi2 = (const float*)d_in[13];

  float* ws   = (float*)d_ws;
  float* part = ws + OFF_PART;
  float* tda  = ws + OFF_TDA;
  float* attn = ws + OFF_ATTN;
  float* inj  = ws + OFF_INJ;

  float* out0 = (float*)d_out;                       // (32,2048,512)
  float* out1 = out0 + (size_t)B * 2048 * D;         // (32,1024,512)
  float* out2 = out1 + (size_t)B * 1024 * D;         // (32, 512,512)
  float* out3 = out2 + (size_t)B * 512 * D;          // (32, 256,512)

  k_stats_partial<<<dim3(B, NCHUNK), 512, 0, stream>>>(level0, part);
  k_stats_reduce<<<B, 512, 0, stream>>>(level0, part, tda);
  k_fft_centroid<<<dim3(256, B), 256, 0, stream>>>(level0, tda);
  k_weights<<<B, 512, 0, stream>>>(tda, w1, b1, w2, b2, wi0, bi0, wi1, bi1, wi2, bi2,
                                   attn, inj);

  // interp + combine (dynamic LDS = 2 * 2S * sizeof(float2) = 32*S bytes)
  k_fft_interp<1024><<<dim3(256, B), 256, 32 * 1024, stream>>>(
      level1, level0, attn, inj + 0ull * B * D, out0);
  k_fft_interp<512><<<dim3(256, B), 256, 32 * 512, stream>>>(
      level2, level1, attn, inj + 1ull * B * D, out1);
  k_fft_interp<256><<<dim3(256, B), 256, 32 * 256, stream>>>(
      level3, level2, attn, inj + 2ull * B * D, out2);

  k_copy4<<<(B * 256 * D / 4 + 255) / 256, 256, 0, stream>>>(
      (const float4*)level3, (float4*)out3, B * 256 * D / 4);
}